// Round 4
// baseline (449.051 us; speedup 1.0000x reference)
//
#include <hip/hip_runtime.h>
#include <hip/hip_bf16.h>
#include <cmath>

using bf16 = __hip_bfloat16;
typedef __attribute__((ext_vector_type(8))) short short8;
typedef __attribute__((ext_vector_type(4))) float f32x4;

#define LDK 72   // padded stride for the small hand-staged tiles (attn, transpose)

__device__ __forceinline__ float bf2f(bf16 v){ return __bfloat162float(v); }
__device__ __forceinline__ bf16 f2bf(float v){ return __float2bfloat16(v); }

// async global->LDS, 16B per lane. LDS dest = wave-uniform base + lane*16.
__device__ __forceinline__ void ld16(const void* g, void* l) {
    __builtin_amdgcn_global_load_lds(
        (const __attribute__((address_space(1))) void*)g,
        (__attribute__((address_space(3))) void*)l, 16, 0, 0);
}

// exp2-based tanh-form GELU (~10 VALU ops vs ~28 for erff); |err| <~1e-3
__device__ __forceinline__ float gelu_f(float x) {
    float u = 0.7978845608028654f * x * (1.0f + 0.044715f * x * x);
    float e = __expf(2.0f * u);
    float t = 1.0f - 2.0f / (e + 1.0f);
    return 0.5f * x * (1.0f + t);
}

// ---------------------------------------------------------------------------
// Fused cast+transpose: out_bf16[C][R] = (bf16)in_f32[R][C]; R,C multiples of 64
// ---------------------------------------------------------------------------
__global__ __launch_bounds__(256) void transpose_f32_bf16(
    const float* __restrict__ in, bf16* __restrict__ out, int R, int C)
{
    __shared__ __align__(16) bf16 tile[64][72];
    const int c0 = blockIdx.x * 64, r0 = blockIdx.y * 64;
    const int t = threadIdx.x;
    const int lr = t >> 3, lc = (t & 7) * 8;
    for (int p = 0; p < 2; ++p) {
        int r = p * 32 + lr;
        const float* src = in + (size_t)(r0 + r) * C + c0 + lc;
        float4 a = *(const float4*)src;
        float4 b = *(const float4*)(src + 4);
        tile[r][lc + 0] = f2bf(a.x); tile[r][lc + 1] = f2bf(a.y);
        tile[r][lc + 2] = f2bf(a.z); tile[r][lc + 3] = f2bf(a.w);
        tile[r][lc + 4] = f2bf(b.x); tile[r][lc + 5] = f2bf(b.y);
        tile[r][lc + 6] = f2bf(b.z); tile[r][lc + 7] = f2bf(b.w);
    }
    __syncthreads();
    for (int p = 0; p < 2; ++p) {
        int r = p * 32 + lr;                    // row within out tile (= col of in tile)
        short8 v;
        for (int j = 0; j < 8; ++j) v[j] = *(const short*)&tile[lc + j][r];
        *(short8*)(out + (size_t)(c0 + r) * R + r0 + lc) = v;
    }
}

// concat bq|bk|bv -> [3072] fp32
__global__ __launch_bounds__(256) void concat_bias(
    const float* __restrict__ bq, const float* __restrict__ bk,
    const float* __restrict__ bv, float* __restrict__ out)
{
    int i = blockIdx.x * 256 + threadIdx.x;    // 0..3071
    const float* src = (i < 1024) ? bq : ((i < 2048) ? bk : bv);
    out[i] = src[i & 1023];
}

// ---------------------------------------------------------------------------
// LayerNorm over D=1024, one block (256 thr) per row. fp32 in -> bf16 out.
// ---------------------------------------------------------------------------
__global__ __launch_bounds__(256) void layernorm_k(
    const float* __restrict__ x, const float* __restrict__ g,
    const float* __restrict__ bta, bf16* __restrict__ out)
{
    const int row = blockIdx.x, t = threadIdx.x;
    const float* xr = x + (size_t)row * 1024;
    float v[4], s1 = 0.f, s2 = 0.f;
    for (int j = 0; j < 4; ++j) {
        float f = xr[j * 256 + t];
        v[j] = f; s1 += f; s2 += f * f;
    }
    for (int d = 1; d < 64; d <<= 1) { s1 += __shfl_xor(s1, d); s2 += __shfl_xor(s2, d); }
    __shared__ float red[2][4];
    int wave = t >> 6, lane = t & 63;
    if (lane == 0) { red[0][wave] = s1; red[1][wave] = s2; }
    __syncthreads();
    s1 = red[0][0] + red[0][1] + red[0][2] + red[0][3];
    s2 = red[1][0] + red[1][1] + red[1][2] + red[1][3];
    float mean = s1 * (1.0f / 1024.0f);
    float var  = s2 * (1.0f / 1024.0f) - mean * mean;
    float rs   = rsqrtf(var + 1e-5f);
    bf16* orow = out + (size_t)row * 1024;
    for (int j = 0; j < 4; ++j) {
        int c = j * 256 + t;
        orow[c] = f2bf((v[j] - mean) * rs * g[c] + bta[c]);
    }
}

// ---------------------------------------------------------------------------
// gemm256: C[M,N] = A[M,K] @ Bt[N,K]^T + bias, 256x256 tile, BK=32, 8 waves
// (2M x 4N), per-wave 128x64 output. Counted-vmcnt double buffer.
// LDS: smem[buf][A|B][256*32] bf16 = 64 KiB -> 2 blocks/CU.
// Per K-tile j (cb=j&1), provably-safe schedule:
//   stage A^(j+1),B^(j+1) -> buf cb^1   (4 loads; regions whose readers all
//                                        passed the previous end-barrier)
//   s_waitcnt vmcnt(4)                  (own tile-j loads landed; ledger:
//                                        4 old + 4 new in flight -> wait to 4)
//   s_barrier                           (=> ALL waves' tile-j staging landed)
//   read 8 A-frags + 4 B-frags from buf cb; 32 MFMA (setprio-wrapped)
//   s_waitcnt lgkmcnt(0); s_barrier     (all reads of buf cb done before any
//                                        wave's next-iteration stage)
// vmcnt never drains to 0 in the main loop (T4); tail iteration uses vmcnt(0).
// Swizzle (both-sides involution, rule #21): source col-group (lane&3) ^
// ((row>>1)&3) pre-applied to the GLOBAL address (LDS dest linear); read
// applies the same XOR: group = lhi ^ ((llo>>1)&3).
// MODE 0: bf16 out | MODE 2: bf16 gelu out. M,N % 256 == 0, K % 32 == 0.
// ---------------------------------------------------------------------------
template <int MODE>
__global__ __launch_bounds__(512, 2) void gemm256(
    const bf16* __restrict__ A, const bf16* __restrict__ Bt,
    const float* __restrict__ bias, void* __restrict__ C,
    int M, int N, int K)
{
    __shared__ __align__(16) bf16 smem[2][2][256 * 32];   // 64 KiB
    const int m0 = blockIdx.x * 256, n0 = blockIdx.y * 256;
    const int t = threadIdx.x;
    const int wave = t >> 6, lane = t & 63, lhi = lane >> 4, llo = lane & 15;
    const int wm = (wave >> 2) * 128;        // M-half of this wave
    const int wn = (wave & 3) * 64;          // N-quarter of this wave

    // staging geometry: LDS slot (q*8+wave)*1024B + lane*16B, q in {0,1}
    // -> row r = q*128 + wave*16 + (lane>>2), linear col-group lane&3.
    // source col-group = (lane&3) ^ ((r>>1)&3); (r+128) gives the same XOR.
    const int r_st = wave * 16 + (lane >> 2);
    const int gsw  = (lane & 3) ^ ((r_st >> 1) & 3);
    const bf16* Abase = A  + (size_t)(m0 + r_st) * K + gsw * 8;
    const bf16* Bbase = Bt + (size_t)(n0 + r_st) * K + gsw * 8;

    auto stageA = [&](int j, int b) {
        const bf16* s = Abase + j * 32;
        ld16(s,                   &smem[b][0][wave * 512]);
        ld16(s + (size_t)128 * K, &smem[b][0][(8 + wave) * 512]);
    };
    auto stageB = [&](int j, int b) {
        const bf16* s = Bbase + j * 32;
        ld16(s,                   &smem[b][1][wave * 512]);
        ld16(s + (size_t)128 * K, &smem[b][1][(8 + wave) * 512]);
    };
    const int grd = (llo >> 1) & 3;          // read-side XOR term
    auto rdA = [&](int b, int mi) {
        return *(const short8*)&smem[b][0][(wm + mi * 16 + llo) * 32 + ((lhi ^ grd) * 8)];
    };
    auto rdB = [&](int b, int ni) {
        return *(const short8*)&smem[b][1][(wn + ni * 16 + llo) * 32 + ((lhi ^ grd) * 8)];
    };

    f32x4 acc[8][4];
    #pragma unroll
    for (int i = 0; i < 8; ++i)
        #pragma unroll
        for (int j = 0; j < 4; ++j) acc[i][j] = (f32x4){0.f, 0.f, 0.f, 0.f};

    const int T = K >> 5;                    // K-tiles of 32
    stageA(0, 0); stageB(0, 0);              // 4 loads in flight

    for (int j = 0; j < T; ++j) {
        const int cb = j & 1;
        if (j + 1 < T) {
            stageA(j + 1, cb ^ 1);           // buf cb^1: all readers passed the
            stageB(j + 1, cb ^ 1);           // previous end-barrier
            asm volatile("s_waitcnt vmcnt(4)" ::: "memory");   // own tile-j landed
        } else {
            asm volatile("s_waitcnt vmcnt(0)" ::: "memory");
        }
        __builtin_amdgcn_sched_barrier(0);
        __builtin_amdgcn_s_barrier();                           // tile j visible to all
        __builtin_amdgcn_sched_barrier(0);

        short8 af[8], bfr[4];
        #pragma unroll
        for (int mi = 0; mi < 8; ++mi) af[mi] = rdA(cb, mi);
        #pragma unroll
        for (int ni = 0; ni < 4; ++ni) bfr[ni] = rdB(cb, ni);
        __builtin_amdgcn_s_setprio(1);
        #pragma unroll
        for (int mi = 0; mi < 8; ++mi)
            #pragma unroll
            for (int ni = 0; ni < 4; ++ni)
                acc[mi][ni] = __builtin_amdgcn_mfma_f32_16x16x32_bf16(
                    af[mi], bfr[ni], acc[mi][ni], 0, 0, 0);
        __builtin_amdgcn_s_setprio(0);

        if (j + 1 < T) {
            asm volatile("s_waitcnt lgkmcnt(0)" ::: "memory");  // reads complete
            __builtin_amdgcn_sched_barrier(0);
            __builtin_amdgcn_s_barrier();                       // before next overwrite
            __builtin_amdgcn_sched_barrier(0);
        }
    }

    #pragma unroll
    for (int mi = 0; mi < 8; ++mi)
        #pragma unroll
        for (int ni = 0; ni < 4; ++ni) {
            int row = m0 + wm + mi * 16 + lhi * 4;
            int col = n0 + wn + ni * 16 + llo;
            float bcol = bias[col];
            #pragma unroll
            for (int r = 0; r < 4; ++r) {
                size_t idx = (size_t)(row + r) * N + col;
                float v = acc[mi][ni][r] + bcol;
                if (MODE == 2) ((bf16*)C)[idx] = f2bf(gelu_f(v));
                else           ((bf16*)C)[idx] = f2bf(v);
            }
        }
}

// ---------------------------------------------------------------------------
// GEMM: C[M,N] = A[M,K] @ Bt[N,K]^T + bias(fp32), fused epilogue.
// MODE 0: bf16 v | MODE 1: f32 v+res | MODE 2: bf16 gelu(v) | MODE 3: f32 v+res
// Tile TM x 128, BK=64, 4 waves (2x2), 16x16x32 bf16 MFMA. m97 single-buffer
// structure (32 KiB LDS). Used for the N=1024 GEMMs where 256-tiles under-fill
// the grid. Requires K % 64 == 0.
// ---------------------------------------------------------------------------
template <int MODE, int TM>
__global__ __launch_bounds__(256) void gemm_bt(
    const bf16* __restrict__ A, const bf16* __restrict__ Bt,
    const float* __restrict__ bias, const float* __restrict__ res,
    void* __restrict__ C, int M, int N, int K)
{
    constexpr int MI = TM / 32;                 // frags per wave in M
    __shared__ __align__(16) bf16 As[TM * 64];
    __shared__ __align__(16) bf16 Bs[128 * 64];
    const int m0 = blockIdx.x * TM, n0 = blockIdx.y * 128;
    const int t = threadIdx.x;
    const int wave = t >> 6, lane = t & 63, lhi = lane >> 4, llo = lane & 15;
    const int wm = (wave & 1) * (TM / 2), wn = (wave >> 1) * 64;
    const int lrow = lane >> 3;                  // 0..7
    const int lcolsw = ((lane & 7) ^ lrow) * 8;  // swizzled source col group

    const bf16* Ag = A  + (size_t)(m0 + lrow) * K + lcolsw;
    const bf16* Bg = Bt + (size_t)(n0 + lrow) * K + lcolsw;

    f32x4 acc[MI][4];
    for (int i = 0; i < MI; ++i)
        for (int j = 0; j < 4; ++j) acc[i][j] = (f32x4){0.f, 0.f, 0.f, 0.f};

    auto issue = [&](int k0) {
        for (int p = 0; p < TM / 32; ++p) {
            int rb = wave * (TM / 4) + p * 8;
            ld16(Ag + (size_t)rb * K + k0, &As[rb * 64]);
        }
        for (int p = 0; p < 4; ++p) {
            int rb = wave * 32 + p * 8;
            ld16(Bg + (size_t)rb * K + k0, &Bs[rb * 64]);
        }
    };
    auto compute = [&]() {
        for (int kk = 0; kk < 64; kk += 32) {
            const int gb = kk >> 3;
            short8 af[MI], bfr[4];
            for (int i = 0; i < MI; ++i) {
                int row = wm + i * 16 + llo;
                af[i] = *(const short8*)&As[row * 64 + (((gb + lhi) ^ (llo & 7)) * 8)];
            }
            for (int i = 0; i < 4; ++i) {
                int row = wn + i * 16 + llo;
                bfr[i] = *(const short8*)&Bs[row * 64 + (((gb + lhi) ^ (llo & 7)) * 8)];
            }
            for (int mi = 0; mi < MI; ++mi)
                for (int ni = 0; ni < 4; ++ni)
                    acc[mi][ni] = __builtin_amdgcn_mfma_f32_16x16x32_bf16(
                        af[mi], bfr[ni], acc[mi][ni], 0, 0, 0);
        }
    };

    issue(0);
    __syncthreads();
    for (int k0 = 0; ; ) {
        compute();
        k0 += 64;
        if (k0 >= K) break;
        __syncthreads();
        issue(k0);
        __syncthreads();
    }

    for (int mi = 0; mi < MI; ++mi)
        for (int ni = 0; ni < 4; ++ni) {
            int row = m0 + wm + mi * 16 + lhi * 4;
            int col = n0 + wn + ni * 16 + llo;
            float bcol = bias[col];
            for (int r = 0; r < 4; ++r) {
                size_t idx = (size_t)(row + r) * N + col;
                float v = acc[mi][ni][r] + bcol;
                if (MODE == 0) {
                    ((bf16*)C)[idx] = f2bf(v);
                } else if (MODE == 1) {
                    ((float*)C)[idx] = v + res[idx];
                } else if (MODE == 2) {
                    ((bf16*)C)[idx] = f2bf(gelu_f(v));
                } else {
                    ((float*)C)[idx] = v + res[idx];
                }
            }
        }
}

// ---------------------------------------------------------------------------
// Block-local attention: one block per (b, h, seq-block of 64).
// qkv: [8192][3072] bf16 (q | k | v each 1024 wide, head h at col h*64)
// attw: [2048][64][64] fp32 (output 1)   o: [8192][1024] bf16
// ---------------------------------------------------------------------------
__global__ __launch_bounds__(256) void attn_kernel(
    const bf16* __restrict__ qkv, float* __restrict__ attw, bf16* __restrict__ o)
{
    __shared__ __align__(16) bf16 qs[64][LDK];
    __shared__ __align__(16) bf16 ks[64][LDK];
    __shared__ __align__(16) bf16 vs[64][LDK];
    const int gid = blockIdx.x;                 // b*512 + h*32 + blk
    const int blk = gid & 31, h = (gid >> 5) & 15, b = gid >> 9;
    const int t = threadIdx.x, wave = t >> 6, lane = t & 63;
    const int lhi = lane >> 4, llo = lane & 15;
    const int srow = t >> 3, scol = (t & 7) * 8;

    for (int p = 0; p < 2; ++p) {
        int r = p * 32 + srow;
        const bf16* base = qkv + (size_t)(b * 2048 + blk * 64 + r) * 3072 + h * 64 + scol;
        *(short8*)&qs[r][scol] = *(const short8*)(base);
        *(short8*)&ks[r][scol] = *(const short8*)(base + 1024);
        *(short8*)&vs[r][scol] = *(const short8*)(base + 2048);
    }
    __syncthreads();

    // scores: wave handles q-rows [16*wave, 16*wave+16)
    f32x4 sacc[4];
    for (int j = 0; j < 4; ++j) sacc[j] = (f32x4){0.f, 0.f, 0.f, 0.f};
    for (int kk = 0; kk < 64; kk += 32) {
        short8 aq = *(const short8*)&qs[wave * 16 + llo][kk + lhi * 8];
        for (int j = 0; j < 4; ++j) {
            short8 bk = *(const short8*)&ks[j * 16 + llo][kk + lhi * 8];
            sacc[j] = __builtin_amdgcn_mfma_f32_16x16x32_bf16(aq, bk, sacc[j], 0, 0, 0);
        }
    }
    // softmax over 64 cols; row = 16*wave + 4*lhi + r lives in 16 lanes (llo) x 4 j
    float inv[4];
    for (int r = 0; r < 4; ++r) {
        float m = -1e30f;
        for (int j = 0; j < 4; ++j) m = fmaxf(m, sacc[j][r]);
        for (int d = 1; d < 16; d <<= 1) m = fmaxf(m, __shfl_xor(m, d));
        float s = 0.f;
        for (int j = 0; j < 4; ++j) {
            float e = expf((sacc[j][r] - m) * 0.125f);
            sacc[j][r] = e; s += e;
        }
        for (int d = 1; d < 16; d <<= 1) s += __shfl_xor(s, d);
        inv[r] = 1.0f / s;
    }
    __syncthreads();   // everyone done reading qs before we overwrite it with P
    const size_t wbase = (size_t)gid * 4096;
    for (int j = 0; j < 4; ++j)
        for (int r = 0; r < 4; ++r) {
            int row = wave * 16 + lhi * 4 + r, col = j * 16 + llo;
            float pw = sacc[j][r] * inv[r];
            qs[row][col] = f2bf(pw);            // P in A-operand source layout
            attw[wbase + row * 64 + col] = pw;  // output 1 (fp32)
        }
    __syncthreads();

    // O = P @ V
    f32x4 oacc[4];
    for (int nt = 0; nt < 4; ++nt) oacc[nt] = (f32x4){0.f, 0.f, 0.f, 0.f};
    for (int kk = 0; kk < 64; kk += 32) {
        short8 aw = *(const short8*)&qs[wave * 16 + llo][kk + lhi * 8];
        for (int nt = 0; nt < 4; ++nt) {
            short8 bv;
            for (int jj = 0; jj < 8; ++jj)
                bv[jj] = *(const short*)&vs[kk + lhi * 8 + jj][nt * 16 + llo];
            oacc[nt] = __builtin_amdgcn_mfma_f32_16x16x32_bf16(aw, bv, oacc[nt], 0, 0, 0);
        }
    }
    for (int nt = 0; nt < 4; ++nt)
        for (int r = 0; r < 4; ++r) {
            int row = wave * 16 + lhi * 4 + r, col = nt * 16 + llo;
            o[(size_t)(b * 2048 + blk * 64 + row) * 1024 + h * 64 + col] = f2bf(oacc[nt][r]);
        }
}

// ---------------------------------------------------------------------------
extern "C" void kernel_launch(void* const* d_in, const int* in_sizes, int n_in,
                              void* d_out, int out_size, void* d_ws, size_t ws_size,
                              hipStream_t stream)
{
    const float* hidden = (const float*)d_in[0];
    const float* ln1_g  = (const float*)d_in[1];
    const float* ln1_b  = (const float*)d_in[2];
    const float* ln2_g  = (const float*)d_in[3];
    const float* ln2_b  = (const float*)d_in[4];
    const float* wq = (const float*)d_in[5];  const float* bq = (const float*)d_in[6];
    const float* wk = (const float*)d_in[7];  const float* bk = (const float*)d_in[8];
    const float* wv = (const float*)d_in[9];  const float* bv = (const float*)d_in[10];
    const float* wo = (const float*)d_in[11]; const float* bo = (const float*)d_in[12];
    const float* w1 = (const float*)d_in[13]; const float* b1 = (const float*)d_in[14];
    const float* w2 = (const float*)d_in[15]; const float* b2 = (const float*)d_in[16];

    char* ws = (char*)d_ws;
    const size_t MB = 1u << 20;
    bf16*  wqkvT   = (bf16*)(ws +  0 * MB);  // [3072][1024]  6MB
    bf16*  woT     = (bf16*)(ws +  6 * MB);  // [1024][1024]  2MB
    bf16*  w1T     = (bf16*)(ws +  8 * MB);  // [4096][1024]  8MB
    bf16*  w2T     = (bf16*)(ws + 16 * MB);  // [1024][4096]  8MB
    float* biasQKV = (float*)(ws + 24 * MB); // 12KB
    bf16*  x       = (bf16*)(ws + 25 * MB);  // [8192][1024] 16MB (x1 then x2)
    bf16*  qkv     = (bf16*)(ws + 41 * MB);  // [8192][3072] 48MB (dead after attn)
    float* hbuf    = (float*)(ws + 41 * MB); // [8192][1024] fp32 32MB, overlays qkv
    bf16*  ffc     = (bf16*)(ws + 73 * MB);  // [8192][4096] 64MB
    bf16*  obuf    = (bf16*)(ws + 89 * MB);  // [8192][1024] 16MB (dead after gemm<1>)

    float* out0 = (float*)d_out;
    float* attw = (float*)d_out + (size_t)8192 * 1024;

    // 1. weights -> bf16, transposed to [N][K]
    transpose_f32_bf16<<<dim3(16, 16), 256, 0, stream>>>(wq, wqkvT,                 1024, 1024);
    transpose_f32_bf16<<<dim3(16, 16), 256, 0, stream>>>(wk, wqkvT + 1024 * 1024,   1024, 1024);
    transpose_f32_bf16<<<dim3(16, 16), 256, 0, stream>>>(wv, wqkvT + 2*1024*1024,   1024, 1024);
    transpose_f32_bf16<<<dim3(16, 16), 256, 0, stream>>>(wo, woT, 1024, 1024);
    transpose_f32_bf16<<<dim3(64, 16), 256, 0, stream>>>(w1, w1T, 1024, 4096);
    transpose_f32_bf16<<<dim3(16, 64), 256, 0, stream>>>(w2, w2T, 4096, 1024);
    concat_bias<<<12, 256, 0, stream>>>(bq, bk, bv, biasQKV);

    // 2. x1 = LN1(hidden)
    layernorm_k<<<8192, 256, 0, stream>>>(hidden, ln1_g, ln1_b, x);

    // 3. qkv = x1 @ [wq|wk|wv]^T + [bq|bk|bv]   (M=8192, N=3072, K=1024)
    gemm256<0><<<dim3(32, 12), 512, 0, stream>>>(x, wqkvT, biasQKV, qkv,
                                                 8192, 3072, 1024);

    // 4. block attention -> attw (fp32, output 1), obuf (bf16)
    attn_kernel<<<2048, 256, 0, stream>>>(qkv, attw, obuf);

    // 5. h = obuf @ wo^T + bo + hidden   (fp32; qkv region is dead now)
    gemm_bt<1, 128><<<dim3(64, 8), 256, 0, stream>>>(obuf, woT, bo, hidden, hbuf,
                                                     8192, 1024, 1024);

    // 6. x2 = LN2(h)
    layernorm_k<<<8192, 256, 0, stream>>>(hbuf, ln2_g, ln2_b, x);

    // 7. ff1 = gelu(x2 @ w1^T + b1)   (M=8192, N=4096, K=1024)
    gemm256<2><<<dim3(32, 16), 512, 0, stream>>>(x, w1T, b1, ffc,
                                                 8192, 4096, 1024);

    // 8. out0 = ff1 @ w2^T + b2 + h   (M=8192, N=1024, K=4096)
    gemm_bt<3, 128><<<dim3(64, 8), 256, 0, stream>>>(ffc, w2T, b2, hbuf, out0,
                                                     8192, 1024, 4096);
}

// Round 5
// 428.002 us; speedup vs baseline: 1.0492x; 1.0492x over previous
//
#include <hip/hip_runtime.h>
#include <hip/hip_bf16.h>
#include <cmath>

using bf16 = __hip_bfloat16;
typedef __attribute__((ext_vector_type(8))) short short8;
typedef __attribute__((ext_vector_type(4))) float f32x4;

#define LDK 72   // padded stride for the small hand-staged tiles (attn, transpose)

__device__ __forceinline__ float bf2f(bf16 v){ return __bfloat162float(v); }
__device__ __forceinline__ bf16 f2bf(float v){ return __float2bfloat16(v); }

// async global->LDS, 16B per lane. LDS dest = wave-uniform base + lane*16.
__device__ __forceinline__ void ld16(const void* g, void* l) {
    __builtin_amdgcn_global_load_lds(
        (const __attribute__((address_space(1))) void*)g,
        (__attribute__((address_space(3))) void*)l, 16, 0, 0);
}

// exp2-based tanh-form GELU (~10 VALU ops vs ~28 for erff); |err| <~1e-3
__device__ __forceinline__ float gelu_f(float x) {
    float u = 0.7978845608028654f * x * (1.0f + 0.044715f * x * x);
    float e = __expf(2.0f * u);
    float t = 1.0f - 2.0f / (e + 1.0f);
    return 0.5f * x * (1.0f + t);
}

// ---------------------------------------------------------------------------
// Fused cast+transpose: out_bf16[C][R] = (bf16)in_f32[R][C]; R,C multiples of 64
// ---------------------------------------------------------------------------
__global__ __launch_bounds__(256) void transpose_f32_bf16(
    const float* __restrict__ in, bf16* __restrict__ out, int R, int C)
{
    __shared__ __align__(16) bf16 tile[64][72];
    const int c0 = blockIdx.x * 64, r0 = blockIdx.y * 64;
    const int t = threadIdx.x;
    const int lr = t >> 3, lc = (t & 7) * 8;
    for (int p = 0; p < 2; ++p) {
        int r = p * 32 + lr;
        const float* src = in + (size_t)(r0 + r) * C + c0 + lc;
        float4 a = *(const float4*)src;
        float4 b = *(const float4*)(src + 4);
        tile[r][lc + 0] = f2bf(a.x); tile[r][lc + 1] = f2bf(a.y);
        tile[r][lc + 2] = f2bf(a.z); tile[r][lc + 3] = f2bf(a.w);
        tile[r][lc + 4] = f2bf(b.x); tile[r][lc + 5] = f2bf(b.y);
        tile[r][lc + 6] = f2bf(b.z); tile[r][lc + 7] = f2bf(b.w);
    }
    __syncthreads();
    for (int p = 0; p < 2; ++p) {
        int r = p * 32 + lr;                    // row within out tile (= col of in tile)
        short8 v;
        for (int j = 0; j < 8; ++j) v[j] = *(const short*)&tile[lc + j][r];
        *(short8*)(out + (size_t)(c0 + r) * R + r0 + lc) = v;
    }
}

// concat bq|bk|bv -> [3072] fp32
__global__ __launch_bounds__(256) void concat_bias(
    const float* __restrict__ bq, const float* __restrict__ bk,
    const float* __restrict__ bv, float* __restrict__ out)
{
    int i = blockIdx.x * 256 + threadIdx.x;    // 0..3071
    const float* src = (i < 1024) ? bq : ((i < 2048) ? bk : bv);
    out[i] = src[i & 1023];
}

// ---------------------------------------------------------------------------
// LayerNorm over D=1024, one block (256 thr) per row. fp32 in -> bf16 out.
// ---------------------------------------------------------------------------
__global__ __launch_bounds__(256) void layernorm_k(
    const float* __restrict__ x, const float* __restrict__ g,
    const float* __restrict__ bta, bf16* __restrict__ out)
{
    const int row = blockIdx.x, t = threadIdx.x;
    const float* xr = x + (size_t)row * 1024;
    float v[4], s1 = 0.f, s2 = 0.f;
    for (int j = 0; j < 4; ++j) {
        float f = xr[j * 256 + t];
        v[j] = f; s1 += f; s2 += f * f;
    }
    for (int d = 1; d < 64; d <<= 1) { s1 += __shfl_xor(s1, d); s2 += __shfl_xor(s2, d); }
    __shared__ float red[2][4];
    int wave = t >> 6, lane = t & 63;
    if (lane == 0) { red[0][wave] = s1; red[1][wave] = s2; }
    __syncthreads();
    s1 = red[0][0] + red[0][1] + red[0][2] + red[0][3];
    s2 = red[1][0] + red[1][1] + red[1][2] + red[1][3];
    float mean = s1 * (1.0f / 1024.0f);
    float var  = s2 * (1.0f / 1024.0f) - mean * mean;
    float rs   = rsqrtf(var + 1e-5f);
    bf16* orow = out + (size_t)row * 1024;
    for (int j = 0; j < 4; ++j) {
        int c = j * 256 + t;
        orow[c] = f2bf((v[j] - mean) * rs * g[c] + bta[c]);
    }
}

// ---------------------------------------------------------------------------
// gemm256: C[M,N] = A[M,K] @ Bt[N,K]^T + bias. 256x256 tile, BK=64, 8 waves
// (2M x 4N), per-wave 128x64 output, 4 phases of 16 MFMA per K-tile.
// LDS: smem[2][A|B][256*64] bf16 = 128 KiB (1 block/CU, like m201).
//
// Stage groups (2 ld16/wave each) match the phase that reads them:
//   A-X = A rows {0-63,128-191}  (mi0-3 rows, both wm)   read at P0
//   B-X = B rows {wn+0..31 all}  (ni0-1 rows)            read at P0 (live->P2)
//   B-Y = B rows {wn+32..63}     (ni2-3)                 read at P1
//   A-Y = A rows {64-127,192-255}(mi4-7)                 read at P2
// During tile j we stage tile j+1 in order A-X,B-X,A-Y,B-Y (one group/phase)
// into buf cb^1 (regions 4+ barriers stale). vmcnt ledger (2 ops/group):
//   P0: after issuing A-X(j+1): outstanding = {A-X,B-X,A-Y,B-Y}(j)+A-X(j+1)
//       = 10 -> vmcnt(6) retires exactly A-X(j),B-X(j); barrier -> collective.
//   P1: after issuing B-X(j+1): 8 outstanding -> vmcnt(4) retires A-Y,B-Y(j).
//   P2/P3: no wait (already retired). Never 0 in-loop (T4). Tail peeled: 4/0.
// Swizzle (zero-conflict, measured on gemm_bt): LDS[r][g]=global[r][g^(r&7)],
// all stage row-bases ===0 mod 8 so source XOR = (lane&7)^lrow; read group
// (kk*4+lhi)^(llo&7).
// MODE 0: bf16 out | MODE 2: bf16 gelu out. M,N % 256 == 0, K == KT.
// ---------------------------------------------------------------------------
template <int MODE, int KT>
__global__ __launch_bounds__(512, 1) void gemm256(
    const bf16* __restrict__ A, const bf16* __restrict__ Bt,
    const float* __restrict__ bias, void* __restrict__ C,
    int M, int N)
{
    __shared__ __align__(16) bf16 smem[2][2][256 * 64];   // 128 KiB
    const int m0 = blockIdx.x * 256, n0 = blockIdx.y * 256;
    const int t = threadIdx.x;
    const int wave = t >> 6, lane = t & 63, lhi = lane >> 4, llo = lane & 15;
    const int wm = (wave >> 2) * 128;        // M-half of this wave
    const int wn = (wave & 3) * 64;          // N-quarter of this wave
    const int lrow = lane >> 3, lcol = lane & 7;
    const int gsrc = (lcol ^ lrow) * 8;      // pre-swizzled source col (elems)

    const bf16* Ag = A  + (size_t)(m0 + lrow) * KT + gsrc;
    const bf16* Bg = Bt + (size_t)(n0 + lrow) * KT + gsrc;

    const int axb = (wave >> 2) * 128 + (wave & 3) * 8;  // A group base (c0)
    const int bxb = (wave & 3) * 64 + (wave >> 2) * 16;  // B group base (c0)

    // stage one A group (yoff=0: A-X, 64: A-Y) of K-tile kt into buf b
    auto stgA = [&](int kt, int b, int yoff) {
        const bf16* s = Ag + (size_t)(axb + yoff) * KT + kt * 64;
        ld16(s,                  &smem[b][0][(axb + yoff) * 64]);
        ld16(s + (size_t)32 * KT, &smem[b][0][(axb + yoff + 32) * 64]);
    };
    // stage one B group (yoff=0: B-X, 32: B-Y)
    auto stgB = [&](int kt, int b, int yoff) {
        const bf16* s = Bg + (size_t)(bxb + yoff) * KT + kt * 64;
        ld16(s,                  &smem[b][1][(bxb + yoff) * 64]);
        ld16(s + (size_t)8 * KT, &smem[b][1][(bxb + yoff + 8) * 64]);
    };
    const int swz = llo & 7;
    auto rdA = [&](int b, int mi, int kk) {
        int R = wm + mi * 16 + llo;
        return *(const short8*)&smem[b][0][R * 64 + (((kk * 4 + lhi) ^ swz) * 8)];
    };
    auto rdB = [&](int b, int ni, int kk) {
        int R = wn + ni * 16 + llo;
        return *(const short8*)&smem[b][1][R * 64 + (((kk * 4 + lhi) ^ swz) * 8)];
    };

    f32x4 acc[8][4];
    #pragma unroll
    for (int i = 0; i < 8; ++i)
        #pragma unroll
        for (int j = 0; j < 4; ++j) acc[i][j] = (f32x4){0.f, 0.f, 0.f, 0.f};

    constexpr int T = KT / 64;               // K-tiles
    // prologue: tile 0, issue order A-X, B-X, A-Y, B-Y (8 vmem ops)
    stgA(0, 0, 0); stgB(0, 0, 0); stgA(0, 0, 64); stgB(0, 0, 32);

#define SB __builtin_amdgcn_sched_barrier(0)

    #pragma unroll 2
    for (int j = 0; j < T - 1; ++j) {
        const int cb = j & 1, nb = cb ^ 1;
        short8 aX[4][2], bX[2][2], aY[4][2], bY[2][2];
        // ---- P0: mi0-3 x ni0-1 ----
        stgA(j + 1, nb, 0);
        asm volatile("s_waitcnt vmcnt(6)" ::: "memory");
        SB; __builtin_amdgcn_s_barrier(); SB;
        #pragma unroll
        for (int mi = 0; mi < 4; ++mi)
            #pragma unroll
            for (int kk = 0; kk < 2; ++kk) aX[mi][kk] = rdA(cb, mi, kk);
        #pragma unroll
        for (int ni = 0; ni < 2; ++ni)
            #pragma unroll
            for (int kk = 0; kk < 2; ++kk) bX[ni][kk] = rdB(cb, ni, kk);
        __builtin_amdgcn_s_setprio(1);
        #pragma unroll
        for (int mi = 0; mi < 4; ++mi)
            #pragma unroll
            for (int ni = 0; ni < 2; ++ni)
                #pragma unroll
                for (int kk = 0; kk < 2; ++kk)
                    acc[mi][ni] = __builtin_amdgcn_mfma_f32_16x16x32_bf16(
                        aX[mi][kk], bX[ni][kk], acc[mi][ni], 0, 0, 0);
        __builtin_amdgcn_s_setprio(0);
        // ---- P1: mi0-3 x ni2-3 ----
        stgB(j + 1, nb, 0);
        asm volatile("s_waitcnt vmcnt(4)" ::: "memory");
        SB; __builtin_amdgcn_s_barrier(); SB;
        #pragma unroll
        for (int ni = 0; ni < 2; ++ni)
            #pragma unroll
            for (int kk = 0; kk < 2; ++kk) bY[ni][kk] = rdB(cb, ni + 2, kk);
        __builtin_amdgcn_s_setprio(1);
        #pragma unroll
        for (int mi = 0; mi < 4; ++mi)
            #pragma unroll
            for (int ni = 0; ni < 2; ++ni)
                #pragma unroll
                for (int kk = 0; kk < 2; ++kk)
                    acc[mi][ni + 2] = __builtin_amdgcn_mfma_f32_16x16x32_bf16(
                        aX[mi][kk], bY[ni][kk], acc[mi][ni + 2], 0, 0, 0);
        __builtin_amdgcn_s_setprio(0);
        // ---- P2: mi4-7 x ni0-1 ----
        stgA(j + 1, nb, 64);
        SB; __builtin_amdgcn_s_barrier(); SB;
        #pragma unroll
        for (int mi = 0; mi < 4; ++mi)
            #pragma unroll
            for (int kk = 0; kk < 2; ++kk) aY[mi][kk] = rdA(cb, mi + 4, kk);
        __builtin_amdgcn_s_setprio(1);
        #pragma unroll
        for (int mi = 0; mi < 4; ++mi)
            #pragma unroll
            for (int ni = 0; ni < 2; ++ni)
                #pragma unroll
                for (int kk = 0; kk < 2; ++kk)
                    acc[mi + 4][ni] = __builtin_amdgcn_mfma_f32_16x16x32_bf16(
                        aY[mi][kk], bX[ni][kk], acc[mi + 4][ni], 0, 0, 0);
        __builtin_amdgcn_s_setprio(0);
        // ---- P3: mi4-7 x ni2-3 ----
        stgB(j + 1, nb, 32);
        SB; __builtin_amdgcn_s_barrier(); SB;
        __builtin_amdgcn_s_setprio(1);
        #pragma unroll
        for (int mi = 0; mi < 4; ++mi)
            #pragma unroll
            for (int ni = 0; ni < 2; ++ni)
                #pragma unroll
                for (int kk = 0; kk < 2; ++kk)
                    acc[mi + 4][ni + 2] = __builtin_amdgcn_mfma_f32_16x16x32_bf16(
                        aY[mi][kk], bY[ni][kk], acc[mi + 4][ni + 2], 0, 0, 0);
        __builtin_amdgcn_s_setprio(0);
    }
    {   // ---- tail tile: no stages; vmcnt 4 then 0 ----
        const int cb = (T - 1) & 1;
        short8 aX[4][2], bX[2][2], aY[4][2], bY[2][2];
        asm volatile("s_waitcnt vmcnt(4)" ::: "memory");
        SB; __builtin_amdgcn_s_barrier(); SB;
        #pragma unroll
        for (int mi = 0; mi < 4; ++mi)
            #pragma unroll
            for (int kk = 0; kk < 2; ++kk) aX[mi][kk] = rdA(cb, mi, kk);
        #pragma unroll
        for (int ni = 0; ni < 2; ++ni)
            #pragma unroll
            for (int kk = 0; kk < 2; ++kk) bX[ni][kk] = rdB(cb, ni, kk);
        __builtin_amdgcn_s_setprio(1);
        #pragma unroll
        for (int mi = 0; mi < 4; ++mi)
            #pragma unroll
            for (int ni = 0; ni < 2; ++ni)
                #pragma unroll
                for (int kk = 0; kk < 2; ++kk)
                    acc[mi][ni] = __builtin_amdgcn_mfma_f32_16x16x32_bf16(
                        aX[mi][kk], bX[ni][kk], acc[mi][ni], 0, 0, 0);
        __builtin_amdgcn_s_setprio(0);
        asm volatile("s_waitcnt vmcnt(0)" ::: "memory");
        SB; __builtin_amdgcn_s_barrier(); SB;
        #pragma unroll
        for (int ni = 0; ni < 2; ++ni)
            #pragma unroll
            for (int kk = 0; kk < 2; ++kk) bY[ni][kk] = rdB(cb, ni + 2, kk);
        #pragma unroll
        for (int mi = 0; mi < 4; ++mi)
            #pragma unroll
            for (int kk = 0; kk < 2; ++kk) aY[mi][kk] = rdA(cb, mi + 4, kk);
        __builtin_amdgcn_s_setprio(1);
        #pragma unroll
        for (int mi = 0; mi < 4; ++mi)
            #pragma unroll
            for (int ni = 0; ni < 2; ++ni)
                #pragma unroll
                for (int kk = 0; kk < 2; ++kk) {
                    acc[mi][ni + 2] = __builtin_amdgcn_mfma_f32_16x16x32_bf16(
                        aX[mi][kk], bY[ni][kk], acc[mi][ni + 2], 0, 0, 0);
                    acc[mi + 4][ni] = __builtin_amdgcn_mfma_f32_16x16x32_bf16(
                        aY[mi][kk], bX[ni][kk], acc[mi + 4][ni], 0, 0, 0);
                    acc[mi + 4][ni + 2] = __builtin_amdgcn_mfma_f32_16x16x32_bf16(
                        aY[mi][kk], bY[ni][kk], acc[mi + 4][ni + 2], 0, 0, 0);
                }
        __builtin_amdgcn_s_setprio(0);
    }
#undef SB

    #pragma unroll
    for (int mi = 0; mi < 8; ++mi)
        #pragma unroll
        for (int ni = 0; ni < 4; ++ni) {
            int row = m0 + wm + mi * 16 + lhi * 4;
            int col = n0 + wn + ni * 16 + llo;
            float bcol = bias[col];
            #pragma unroll
            for (int r = 0; r < 4; ++r) {
                size_t idx = (size_t)(row + r) * N + col;
                float v = acc[mi][ni][r] + bcol;
                if (MODE == 2) ((bf16*)C)[idx] = f2bf(gelu_f(v));
                else           ((bf16*)C)[idx] = f2bf(v);
            }
        }
}

// ---------------------------------------------------------------------------
// GEMM: C[M,N] = A[M,K] @ Bt[N,K]^T + bias(fp32), fused epilogue.
// MODE 0: bf16 v | MODE 1: f32 v+res | MODE 2: bf16 gelu(v) | MODE 3: f32 v+res
// Tile TM x 128, BK=64, 4 waves (2x2), 16x16x32 bf16 MFMA. m97 single-buffer
// structure (32 KiB LDS). Used for the N=1024 GEMMs where 256-tiles under-fill
// the grid. Requires K % 64 == 0.
// ---------------------------------------------------------------------------
template <int MODE, int TM>
__global__ __launch_bounds__(256) void gemm_bt(
    const bf16* __restrict__ A, const bf16* __restrict__ Bt,
    const float* __restrict__ bias, const float* __restrict__ res,
    void* __restrict__ C, int M, int N, int K)
{
    constexpr int MI = TM / 32;                 // frags per wave in M
    __shared__ __align__(16) bf16 As[TM * 64];
    __shared__ __align__(16) bf16 Bs[128 * 64];
    const int m0 = blockIdx.x * TM, n0 = blockIdx.y * 128;
    const int t = threadIdx.x;
    const int wave = t >> 6, lane = t & 63, lhi = lane >> 4, llo = lane & 15;
    const int wm = (wave & 1) * (TM / 2), wn = (wave >> 1) * 64;
    const int lrow = lane >> 3;                  // 0..7
    const int lcolsw = ((lane & 7) ^ lrow) * 8;  // swizzled source col group

    const bf16* Ag = A  + (size_t)(m0 + lrow) * K + lcolsw;
    const bf16* Bg = Bt + (size_t)(n0 + lrow) * K + lcolsw;

    f32x4 acc[MI][4];
    for (int i = 0; i < MI; ++i)
        for (int j = 0; j < 4; ++j) acc[i][j] = (f32x4){0.f, 0.f, 0.f, 0.f};

    auto issue = [&](int k0) {
        for (int p = 0; p < TM / 32; ++p) {
            int rb = wave * (TM / 4) + p * 8;
            ld16(Ag + (size_t)rb * K + k0, &As[rb * 64]);
        }
        for (int p = 0; p < 4; ++p) {
            int rb = wave * 32 + p * 8;
            ld16(Bg + (size_t)rb * K + k0, &Bs[rb * 64]);
        }
    };
    auto compute = [&]() {
        for (int kk = 0; kk < 64; kk += 32) {
            const int gb = kk >> 3;
            short8 af[MI], bfr[4];
            for (int i = 0; i < MI; ++i) {
                int row = wm + i * 16 + llo;
                af[i] = *(const short8*)&As[row * 64 + (((gb + lhi) ^ (llo & 7)) * 8)];
            }
            for (int i = 0; i < 4; ++i) {
                int row = wn + i * 16 + llo;
                bfr[i] = *(const short8*)&Bs[row * 64 + (((gb + lhi) ^ (llo & 7)) * 8)];
            }
            for (int mi = 0; mi < MI; ++mi)
                for (int ni = 0; ni < 4; ++ni)
                    acc[mi][ni] = __builtin_amdgcn_mfma_f32_16x16x32_bf16(
                        af[mi], bfr[ni], acc[mi][ni], 0, 0, 0);
        }
    };

    issue(0);
    __syncthreads();
    for (int k0 = 0; ; ) {
        compute();
        k0 += 64;
        if (k0 >= K) break;
        __syncthreads();
        issue(k0);
        __syncthreads();
    }

    for (int mi = 0; mi < MI; ++mi)
        for (int ni = 0; ni < 4; ++ni) {
            int row = m0 + wm + mi * 16 + lhi * 4;
            int col = n0 + wn + ni * 16 + llo;
            float bcol = bias[col];
            for (int r = 0; r < 4; ++r) {
                size_t idx = (size_t)(row + r) * N + col;
                float v = acc[mi][ni][r] + bcol;
                if (MODE == 0) {
                    ((bf16*)C)[idx] = f2bf(v);
                } else if (MODE == 1) {
                    ((float*)C)[idx] = v + res[idx];
                } else if (MODE == 2) {
                    ((bf16*)C)[idx] = f2bf(gelu_f(v));
                } else {
                    ((float*)C)[idx] = v + res[idx];
                }
            }
        }
}

// ---------------------------------------------------------------------------
// Block-local attention: one block per (b, h, seq-block of 64).
// qkv: [8192][3072] bf16 (q | k | v each 1024 wide, head h at col h*64)
// attw: [2048][64][64] fp32 (output 1)   o: [8192][1024] bf16
// ---------------------------------------------------------------------------
__global__ __launch_bounds__(256) void attn_kernel(
    const bf16* __restrict__ qkv, float* __restrict__ attw, bf16* __restrict__ o)
{
    __shared__ __align__(16) bf16 qs[64][LDK];
    __shared__ __align__(16) bf16 ks[64][LDK];
    __shared__ __align__(16) bf16 vs[64][LDK];
    const int gid = blockIdx.x;                 // b*512 + h*32 + blk
    const int blk = gid & 31, h = (gid >> 5) & 15, b = gid >> 9;
    const int t = threadIdx.x, wave = t >> 6, lane = t & 63;
    const int lhi = lane >> 4, llo = lane & 15;
    const int srow = t >> 3, scol = (t & 7) * 8;

    for (int p = 0; p < 2; ++p) {
        int r = p * 32 + srow;
        const bf16* base = qkv + (size_t)(b * 2048 + blk * 64 + r) * 3072 + h * 64 + scol;
        *(short8*)&qs[r][scol] = *(const short8*)(base);
        *(short8*)&ks[r][scol] = *(const short8*)(base + 1024);
        *(short8*)&vs[r][scol] = *(const short8*)(base + 2048);
    }
    __syncthreads();

    // scores: wave handles q-rows [16*wave, 16*wave+16)
    f32x4 sacc[4];
    for (int j = 0; j < 4; ++j) sacc[j] = (f32x4){0.f, 0.f, 0.f, 0.f};
    for (int kk = 0; kk < 64; kk += 32) {
        short8 aq = *(const short8*)&qs[wave * 16 + llo][kk + lhi * 8];
        for (int j = 0; j < 4; ++j) {
            short8 bk = *(const short8*)&ks[j * 16 + llo][kk + lhi * 8];
            sacc[j] = __builtin_amdgcn_mfma_f32_16x16x32_bf16(aq, bk, sacc[j], 0, 0, 0);
        }
    }
    // softmax over 64 cols; row = 16*wave + 4*lhi + r lives in 16 lanes (llo) x 4 j
    float inv[4];
    for (int r = 0; r < 4; ++r) {
        float m = -1e30f;
        for (int j = 0; j < 4; ++j) m = fmaxf(m, sacc[j][r]);
        for (int d = 1; d < 16; d <<= 1) m = fmaxf(m, __shfl_xor(m, d));
        float s = 0.f;
        for (int j = 0; j < 4; ++j) {
            float e = expf((sacc[j][r] - m) * 0.125f);
            sacc[j][r] = e; s += e;
        }
        for (int d = 1; d < 16; d <<= 1) s += __shfl_xor(s, d);
        inv[r] = 1.0f / s;
    }
    __syncthreads();   // everyone done reading qs before we overwrite it with P
    const size_t wbase = (size_t)gid * 4096;
    for (int j = 0; j < 4; ++j)
        for (int r = 0; r < 4; ++r) {
            int row = wave * 16 + lhi * 4 + r, col = j * 16 + llo;
            float pw = sacc[j][r] * inv[r];
            qs[row][col] = f2bf(pw);            // P in A-operand source layout
            attw[wbase + row * 64 + col] = pw;  // output 1 (fp32)
        }
    __syncthreads();

    // O = P @ V
    f32x4 oacc[4];
    for (int nt = 0; nt < 4; ++nt) oacc[nt] = (f32x4){0.f, 0.f, 0.f, 0.f};
    for (int kk = 0; kk < 64; kk += 32) {
        short8 aw = *(const short8*)&qs[wave * 16 + llo][kk + lhi * 8];
        for (int nt = 0; nt < 4; ++nt) {
            short8 bv;
            for (int jj = 0; jj < 8; ++jj)
                bv[jj] = *(const short*)&vs[kk + lhi * 8 + jj][nt * 16 + llo];
            oacc[nt] = __builtin_amdgcn_mfma_f32_16x16x32_bf16(aw, bv, oacc[nt], 0, 0, 0);
        }
    }
    for (int nt = 0; nt < 4; ++nt)
        for (int r = 0; r < 4; ++r) {
            int row = wave * 16 + lhi * 4 + r, col = nt * 16 + llo;
            o[(size_t)(b * 2048 + blk * 64 + row) * 1024 + h * 64 + col] = f2bf(oacc[nt][r]);
        }
}

// ---------------------------------------------------------------------------
extern "C" void kernel_launch(void* const* d_in, const int* in_sizes, int n_in,
                              void* d_out, int out_size, void* d_ws, size_t ws_size,
                              hipStream_t stream)
{
    const float* hidden = (const float*)d_in[0];
    const float* ln1_g  = (const float*)d_in[1];
    const float* ln1_b  = (const float*)d_in[2];
    const float* ln2_g  = (const float*)d_in[3];
    const float* ln2_b  = (const float*)d_in[4];
    const float* wq = (const float*)d_in[5];  const float* bq = (const float*)d_in[6];
    const float* wk = (const float*)d_in[7];  const float* bk = (const float*)d_in[8];
    const float* wv = (const float*)d_in[9];  const float* bv = (const float*)d_in[10];
    const float* wo = (const float*)d_in[11]; const float* bo = (const float*)d_in[12];
    const float* w1 = (const float*)d_in[13]; const float* b1 = (const float*)d_in[14];
    const float* w2 = (const float*)d_in[15]; const float* b2 = (const float*)d_in[16];

    char* ws = (char*)d_ws;
    const size_t MB = 1u << 20;
    bf16*  wqkvT   = (bf16*)(ws +  0 * MB);  // [3072][1024]  6MB
    bf16*  woT     = (bf16*)(ws +  6 * MB);  // [1024][1024]  2MB
    bf16*  w1T     = (bf16*)(ws +  8 * MB);  // [4096][1024]  8MB
    bf16*  w2T     = (bf16*)(ws + 16 * MB);  // [1024][4096]  8MB
    float* biasQKV = (float*)(ws + 24 * MB); // 12KB
    bf16*  x       = (bf16*)(ws + 25 * MB);  // [8192][1024] 16MB (x1 then x2)
    bf16*  qkv     = (bf16*)(ws + 41 * MB);  // [8192][3072] 48MB (dead after attn)
    float* hbuf    = (float*)(ws + 41 * MB); // [8192][1024] fp32 32MB, overlays qkv
    bf16*  ffc     = (bf16*)(ws + 73 * MB);  // [8192][4096] 64MB
    bf16*  obuf    = (bf16*)(ws + 89 * MB);  // [8192][1024] 16MB (dead after gemm<1>)

    float* out0 = (float*)d_out;
    float* attw = (float*)d_out + (size_t)8192 * 1024;

    // 1. weights -> bf16, transposed to [N][K]
    transpose_f32_bf16<<<dim3(16, 16), 256, 0, stream>>>(wq, wqkvT,                 1024, 1024);
    transpose_f32_bf16<<<dim3(16, 16), 256, 0, stream>>>(wk, wqkvT + 1024 * 1024,   1024, 1024);
    transpose_f32_bf16<<<dim3(16, 16), 256, 0, stream>>>(wv, wqkvT + 2*1024*1024,   1024, 1024);
    transpose_f32_bf16<<<dim3(16, 16), 256, 0, stream>>>(wo, woT, 1024, 1024);
    transpose_f32_bf16<<<dim3(64, 16), 256, 0, stream>>>(w1, w1T, 1024, 4096);
    transpose_f32_bf16<<<dim3(16, 64), 256, 0, stream>>>(w2, w2T, 4096, 1024);
    concat_bias<<<12, 256, 0, stream>>>(bq, bk, bv, biasQKV);

    // 2. x1 = LN1(hidden)
    layernorm_k<<<8192, 256, 0, stream>>>(hidden, ln1_g, ln1_b, x);

    // 3. qkv = x1 @ [wq|wk|wv]^T + [bq|bk|bv]   (M=8192, N=3072, K=1024)
    gemm256<0, 1024><<<dim3(32, 12), 512, 0, stream>>>(x, wqkvT, biasQKV, qkv,
                                                       8192, 3072);

    // 4. block attention -> attw (fp32, output 1), obuf (bf16)
    attn_kernel<<<2048, 256, 0, stream>>>(qkv, attw, obuf);

    // 5. h = obuf @ wo^T + bo + hidden   (fp32; qkv region is dead now)
    gemm_bt<1, 128><<<dim3(64, 8), 256, 0, stream>>>(obuf, woT, bo, hidden, hbuf,
                                                     8192, 1024, 1024);

    // 6. x2 = LN2(h)
    layernorm_k<<<8192, 256, 0, stream>>>(hbuf, ln2_g, ln2_b, x);

    // 7. ff1 = gelu(x2 @ w1^T + b1)   (M=8192, N=4096, K=1024)
    gemm256<2, 1024><<<dim3(32, 16), 512, 0, stream>>>(x, w1T, b1, ffc,
                                                       8192, 4096);

    // 8. out0 = ff1 @ w2^T + b2 + h   (M=8192, N=1024, K=4096)
    gemm_bt<3, 128><<<dim3(64, 8), 256, 0, stream>>>(ffc, w2T, b2, hbuf, out0,
                                                     8192, 1024, 4096);
}

// Round 6
// 418.620 us; speedup vs baseline: 1.0727x; 1.0224x over previous
//
#include <hip/hip_runtime.h>
#include <hip/hip_bf16.h>
#include <cmath>
#include <type_traits>

using bf16 = __hip_bfloat16;
typedef __attribute__((ext_vector_type(8))) short short8;
typedef __attribute__((ext_vector_type(4))) float f32x4;

#define LDK 72   // padded stride for the small hand-staged tiles (attn, transpose)

__device__ __forceinline__ float bf2f(bf16 v){ return __bfloat162float(v); }
__device__ __forceinline__ bf16 f2bf(float v){ return __float2bfloat16(v); }

// async global->LDS, 16B per lane. LDS dest = wave-uniform base + lane*16.
__device__ __forceinline__ void ld16(const void* g, void* l) {
    __builtin_amdgcn_global_load_lds(
        (const __attribute__((address_space(1))) void*)g,
        (__attribute__((address_space(3))) void*)l, 16, 0, 0);
}

// exp2-based tanh-form GELU (~10 VALU ops vs ~28 for erff); |err| <~1e-3
__device__ __forceinline__ float gelu_f(float x) {
    float u = 0.7978845608028654f * x * (1.0f + 0.044715f * x * x);
    float e = __expf(2.0f * u);
    float t = 1.0f - 2.0f / (e + 1.0f);
    return 0.5f * x * (1.0f + t);
}

// ---------------------------------------------------------------------------
// Fused cast+transpose: out_bf16[C][R] = (bf16)in_f32[R][C]; R,C multiples of 64
// ---------------------------------------------------------------------------
__global__ __launch_bounds__(256) void transpose_f32_bf16(
    const float* __restrict__ in, bf16* __restrict__ out, int R, int C)
{
    __shared__ __align__(16) bf16 tile[64][72];
    const int c0 = blockIdx.x * 64, r0 = blockIdx.y * 64;
    const int t = threadIdx.x;
    const int lr = t >> 3, lc = (t & 7) * 8;
    for (int p = 0; p < 2; ++p) {
        int r = p * 32 + lr;
        const float* src = in + (size_t)(r0 + r) * C + c0 + lc;
        float4 a = *(const float4*)src;
        float4 b = *(const float4*)(src + 4);
        tile[r][lc + 0] = f2bf(a.x); tile[r][lc + 1] = f2bf(a.y);
        tile[r][lc + 2] = f2bf(a.z); tile[r][lc + 3] = f2bf(a.w);
        tile[r][lc + 4] = f2bf(b.x); tile[r][lc + 5] = f2bf(b.y);
        tile[r][lc + 6] = f2bf(b.z); tile[r][lc + 7] = f2bf(b.w);
    }
    __syncthreads();
    for (int p = 0; p < 2; ++p) {
        int r = p * 32 + lr;                    // row within out tile (= col of in tile)
        short8 v;
        for (int j = 0; j < 8; ++j) v[j] = *(const short*)&tile[lc + j][r];
        *(short8*)(out + (size_t)(c0 + r) * R + r0 + lc) = v;
    }
}

// concat bq|bk|bv -> [3072] fp32
__global__ __launch_bounds__(256) void concat_bias(
    const float* __restrict__ bq, const float* __restrict__ bk,
    const float* __restrict__ bv, float* __restrict__ out)
{
    int i = blockIdx.x * 256 + threadIdx.x;    // 0..3071
    const float* src = (i < 1024) ? bq : ((i < 2048) ? bk : bv);
    out[i] = src[i & 1023];
}

// ---------------------------------------------------------------------------
// LayerNorm over D=1024, one block (256 thr) per row. fp32 in -> bf16 out.
// ---------------------------------------------------------------------------
__global__ __launch_bounds__(256) void layernorm_k(
    const float* __restrict__ x, const float* __restrict__ g,
    const float* __restrict__ bta, bf16* __restrict__ out)
{
    const int row = blockIdx.x, t = threadIdx.x;
    const float* xr = x + (size_t)row * 1024;
    float v[4], s1 = 0.f, s2 = 0.f;
    for (int j = 0; j < 4; ++j) {
        float f = xr[j * 256 + t];
        v[j] = f; s1 += f; s2 += f * f;
    }
    for (int d = 1; d < 64; d <<= 1) { s1 += __shfl_xor(s1, d); s2 += __shfl_xor(s2, d); }
    __shared__ float red[2][4];
    int wave = t >> 6, lane = t & 63;
    if (lane == 0) { red[0][wave] = s1; red[1][wave] = s2; }
    __syncthreads();
    s1 = red[0][0] + red[0][1] + red[0][2] + red[0][3];
    s2 = red[1][0] + red[1][1] + red[1][2] + red[1][3];
    float mean = s1 * (1.0f / 1024.0f);
    float var  = s2 * (1.0f / 1024.0f) - mean * mean;
    float rs   = rsqrtf(var + 1e-5f);
    bf16* orow = out + (size_t)row * 1024;
    for (int j = 0; j < 4; ++j) {
        int c = j * 256 + t;
        orow[c] = f2bf((v[j] - mean) * rs * g[c] + bta[c]);
    }
}

// ---------------------------------------------------------------------------
// gemm256: C[M,N] = A[M,K] @ Bt[N,K]^T + bias. 256x256 tile, BK=64, 8 waves
// (2M x 4N), per-wave 128x64 output, 4 phases of 16 MFMA per K-tile.
// LDS: smem[2][A|B][256*64] bf16 = 128 KiB (1 block/CU).
//
// v3 (this round): same schedule as v2 (passed, ledger verified) but ALL loop
// addressing strength-reduced to loop-invariant registers:
//   - ds_reads: 4 precomputed element offsets (offA0/offA1/offB0/offB1);
//     every read = base_voff + compile-time imm (mi*1024 elems) -> 0 VALU/read.
//   - stages: 8 incrementing global pointers (+64 elems/tile), LDS dests
//     constant-folded (buf idx is a compile-time integral_constant).
//   - P2 barrier dropped (visibility of A-Y/B-Y established at P1's
//     vmcnt(4)+barrier; P2 stage writes only buf nb, unread this tile).
//   - lgkmcnt(0) added before the P3 WAR barrier (all ds_reads of buf cb
//     complete before any wave's next-tile stage overwrites cb).
// vmcnt ledger (2 ops/group, groups staged in order A-X,B-X,A-Y,B-Y):
//   P0 issue A-X(j+1): 10 out -> vmcnt(6) retires A-X(j),B-X(j); barrier.
//   P1 issue B-X(j+1): 8 out  -> vmcnt(4) retires A-Y(j),B-Y(j); barrier.
//   P2 issue A-Y(j+1); P3 issue B-Y(j+1): no waits. Never 0 in-loop (T4).
// Swizzle (zero-conflict, verified): LDS[r][g]=global[r][g^(r&7)]; source XOR
// (lane&7)^lrow; read group (kk*4+lhi)^(llo&7).
// MODE 0: bf16 out | MODE 2: bf16 gelu out. M,N % 256 == 0, K == KT, KT/64 even.
// ---------------------------------------------------------------------------
template <int MODE, int KT>
__global__ __launch_bounds__(512, 1) void gemm256(
    const bf16* __restrict__ A, const bf16* __restrict__ Bt,
    const float* __restrict__ bias, void* __restrict__ C,
    int M, int N)
{
    __shared__ __align__(16) bf16 smem[2][2][256 * 64];   // 128 KiB
    const int m0 = blockIdx.x * 256, n0 = blockIdx.y * 256;
    const int t = threadIdx.x;
    const int wave = t >> 6, lane = t & 63, lhi = lane >> 4, llo = lane & 15;
    const int wm = (wave >> 2) * 128;        // M-half of this wave
    const int wn = (wave & 3) * 64;          // N-quarter of this wave
    const int lrow = lane >> 3, lcol = lane & 7;
    const int gsrc = (lcol ^ lrow) * 8;      // pre-swizzled source col (elems)

    const int axb = (wave >> 2) * 128 + (wave & 3) * 8;  // A stage row base
    const int bxb = (wave & 3) * 64 + (wave >> 2) * 16;  // B stage row base

    // 8 incrementing global stage pointers (advance +64 elems per K-tile)
    const bf16* gAX0 = A  + (size_t)(m0 + lrow + axb) * KT + gsrc;
    const bf16* gAX1 = gAX0 + (size_t)32 * KT;
    const bf16* gAY0 = gAX0 + (size_t)64 * KT;
    const bf16* gAY1 = gAX0 + (size_t)96 * KT;
    const bf16* gBX0 = Bt + (size_t)(n0 + lrow + bxb) * KT + gsrc;
    const bf16* gBX1 = gBX0 + (size_t)8 * KT;
    const bf16* gBY0 = gBX0 + (size_t)32 * KT;
    const bf16* gBY1 = gBX0 + (size_t)40 * KT;

    // loop-invariant ds_read element offsets (kk=0 / kk=1 groups)
    const int swz   = llo & 7;
    const int offA0 = (wm + llo) * 64 + ((lhi ^ swz) * 8);
    const int offA1 = (wm + llo) * 64 + ((((4 + lhi)) ^ swz) * 8);
    const int offB0 = (wn + llo) * 64 + ((lhi ^ swz) * 8);
    const int offB1 = (wn + llo) * 64 + ((((4 + lhi)) ^ swz) * 8);

    f32x4 acc[8][4];
    #pragma unroll
    for (int i = 0; i < 8; ++i)
        #pragma unroll
        for (int j = 0; j < 4; ++j) acc[i][j] = (f32x4){0.f, 0.f, 0.f, 0.f};

    constexpr int T = KT / 64;               // K-tiles
    static_assert(T % 2 == 0, "tail assumes even tile count");

#define SBR __builtin_amdgcn_sched_barrier(0)

    // prologue: stage tile 0 into buf 0 (order A-X, B-X, A-Y, B-Y), advance
    ld16(gAX0, &smem[0][0][axb * 64]);        ld16(gAX1, &smem[0][0][(axb + 32) * 64]);
    ld16(gBX0, &smem[0][1][bxb * 64]);        ld16(gBX1, &smem[0][1][(bxb + 8) * 64]);
    ld16(gAY0, &smem[0][0][(axb + 64) * 64]); ld16(gAY1, &smem[0][0][(axb + 96) * 64]);
    ld16(gBY0, &smem[0][1][(bxb + 32) * 64]); ld16(gBY1, &smem[0][1][(bxb + 40) * 64]);
    gAX0 += 64; gAX1 += 64; gAY0 += 64; gAY1 += 64;
    gBX0 += 64; gBX1 += 64; gBY0 += 64; gBY1 += 64;

    auto tile = [&](auto cbc) __attribute__((always_inline)) {
        constexpr int CB = decltype(cbc)::value;
        constexpr int NB = CB ^ 1;
        short8 aX[4][2], bX[2][2], aY[4][2], bY[2][2];
        // ---- P0: stage A-X(j+1); vmcnt(6); bar; read aX,bX; MFMA q0 ----
        ld16(gAX0, &smem[NB][0][axb * 64]);
        ld16(gAX1, &smem[NB][0][(axb + 32) * 64]);
        asm volatile("s_waitcnt vmcnt(6)" ::: "memory");
        SBR; __builtin_amdgcn_s_barrier(); SBR;
        #pragma unroll
        for (int mi = 0; mi < 4; ++mi) {
            aX[mi][0] = *(const short8*)&smem[CB][0][offA0 + mi * 1024];
            aX[mi][1] = *(const short8*)&smem[CB][0][offA1 + mi * 1024];
        }
        #pragma unroll
        for (int ni = 0; ni < 2; ++ni) {
            bX[ni][0] = *(const short8*)&smem[CB][1][offB0 + ni * 1024];
            bX[ni][1] = *(const short8*)&smem[CB][1][offB1 + ni * 1024];
        }
        __builtin_amdgcn_s_setprio(1);
        #pragma unroll
        for (int mi = 0; mi < 4; ++mi)
            #pragma unroll
            for (int ni = 0; ni < 2; ++ni)
                #pragma unroll
                for (int kk = 0; kk < 2; ++kk)
                    acc[mi][ni] = __builtin_amdgcn_mfma_f32_16x16x32_bf16(
                        aX[mi][kk], bX[ni][kk], acc[mi][ni], 0, 0, 0);
        __builtin_amdgcn_s_setprio(0);
        // ---- P1: stage B-X(j+1); vmcnt(4); bar; read bY; MFMA q1 ----
        ld16(gBX0, &smem[NB][1][bxb * 64]);
        ld16(gBX1, &smem[NB][1][(bxb + 8) * 64]);
        asm volatile("s_waitcnt vmcnt(4)" ::: "memory");
        SBR; __builtin_amdgcn_s_barrier(); SBR;
        #pragma unroll
        for (int ni = 0; ni < 2; ++ni) {
            bY[ni][0] = *(const short8*)&smem[CB][1][offB0 + (ni + 2) * 1024];
            bY[ni][1] = *(const short8*)&smem[CB][1][offB1 + (ni + 2) * 1024];
        }
        __builtin_amdgcn_s_setprio(1);
        #pragma unroll
        for (int mi = 0; mi < 4; ++mi)
            #pragma unroll
            for (int ni = 0; ni < 2; ++ni)
                #pragma unroll
                for (int kk = 0; kk < 2; ++kk)
                    acc[mi][ni + 2] = __builtin_amdgcn_mfma_f32_16x16x32_bf16(
                        aX[mi][kk], bY[ni][kk], acc[mi][ni + 2], 0, 0, 0);
        __builtin_amdgcn_s_setprio(0);
        // ---- P2: stage A-Y(j+1); (no barrier) read aY; MFMA q2 ----
        ld16(gAY0, &smem[NB][0][(axb + 64) * 64]);
        ld16(gAY1, &smem[NB][0][(axb + 96) * 64]);
        #pragma unroll
        for (int mi = 0; mi < 4; ++mi) {
            aY[mi][0] = *(const short8*)&smem[CB][0][offA0 + (mi + 4) * 1024];
            aY[mi][1] = *(const short8*)&smem[CB][0][offA1 + (mi + 4) * 1024];
        }
        __builtin_amdgcn_s_setprio(1);
        #pragma unroll
        for (int mi = 0; mi < 4; ++mi)
            #pragma unroll
            for (int ni = 0; ni < 2; ++ni)
                #pragma unroll
                for (int kk = 0; kk < 2; ++kk)
                    acc[mi + 4][ni] = __builtin_amdgcn_mfma_f32_16x16x32_bf16(
                        aY[mi][kk], bX[ni][kk], acc[mi + 4][ni], 0, 0, 0);
        __builtin_amdgcn_s_setprio(0);
        // ---- P3: stage B-Y(j+1); lgkmcnt(0); WAR bar; MFMA q3 ----
        ld16(gBY0, &smem[NB][1][(bxb + 32) * 64]);
        ld16(gBY1, &smem[NB][1][(bxb + 40) * 64]);
        asm volatile("s_waitcnt lgkmcnt(0)" ::: "memory");
        SBR; __builtin_amdgcn_s_barrier(); SBR;
        __builtin_amdgcn_s_setprio(1);
        #pragma unroll
        for (int mi = 0; mi < 4; ++mi)
            #pragma unroll
            for (int ni = 0; ni < 2; ++ni)
                #pragma unroll
                for (int kk = 0; kk < 2; ++kk)
                    acc[mi + 4][ni + 2] = __builtin_amdgcn_mfma_f32_16x16x32_bf16(
                        aY[mi][kk], bY[ni][kk], acc[mi + 4][ni + 2], 0, 0, 0);
        __builtin_amdgcn_s_setprio(0);
        gAX0 += 64; gAX1 += 64; gAY0 += 64; gAY1 += 64;
        gBX0 += 64; gBX1 += 64; gBY0 += 64; gBY1 += 64;
    };

    for (int jp = 0; jp < (T - 2) / 2; ++jp) {
        tile(std::integral_constant<int, 0>{});
        tile(std::integral_constant<int, 1>{});
    }
    tile(std::integral_constant<int, 0>{});   // j = T-2, reads buf0, stages tile T-1 -> buf1

    {   // ---- tail tile (buf 1): no stages; vmcnt 4 then 0 ----
        short8 aX[4][2], bX[2][2], aY[4][2], bY[2][2];
        asm volatile("s_waitcnt vmcnt(4)" ::: "memory");
        SBR; __builtin_amdgcn_s_barrier(); SBR;
        #pragma unroll
        for (int mi = 0; mi < 4; ++mi) {
            aX[mi][0] = *(const short8*)&smem[1][0][offA0 + mi * 1024];
            aX[mi][1] = *(const short8*)&smem[1][0][offA1 + mi * 1024];
        }
        #pragma unroll
        for (int ni = 0; ni < 2; ++ni) {
            bX[ni][0] = *(const short8*)&smem[1][1][offB0 + ni * 1024];
            bX[ni][1] = *(const short8*)&smem[1][1][offB1 + ni * 1024];
        }
        __builtin_amdgcn_s_setprio(1);
        #pragma unroll
        for (int mi = 0; mi < 4; ++mi)
            #pragma unroll
            for (int ni = 0; ni < 2; ++ni)
                #pragma unroll
                for (int kk = 0; kk < 2; ++kk)
                    acc[mi][ni] = __builtin_amdgcn_mfma_f32_16x16x32_bf16(
                        aX[mi][kk], bX[ni][kk], acc[mi][ni], 0, 0, 0);
        __builtin_amdgcn_s_setprio(0);
        asm volatile("s_waitcnt vmcnt(0)" ::: "memory");
        SBR; __builtin_amdgcn_s_barrier(); SBR;
        #pragma unroll
        for (int ni = 0; ni < 2; ++ni) {
            bY[ni][0] = *(const short8*)&smem[1][1][offB0 + (ni + 2) * 1024];
            bY[ni][1] = *(const short8*)&smem[1][1][offB1 + (ni + 2) * 1024];
        }
        #pragma unroll
        for (int mi = 0; mi < 4; ++mi) {
            aY[mi][0] = *(const short8*)&smem[1][0][offA0 + (mi + 4) * 1024];
            aY[mi][1] = *(const short8*)&smem[1][0][offA1 + (mi + 4) * 1024];
        }
        __builtin_amdgcn_s_setprio(1);
        #pragma unroll
        for (int mi = 0; mi < 4; ++mi)
            #pragma unroll
            for (int ni = 0; ni < 2; ++ni)
                #pragma unroll
                for (int kk = 0; kk < 2; ++kk) {
                    acc[mi][ni + 2] = __builtin_amdgcn_mfma_f32_16x16x32_bf16(
                        aX[mi][kk], bY[ni][kk], acc[mi][ni + 2], 0, 0, 0);
                    acc[mi + 4][ni] = __builtin_amdgcn_mfma_f32_16x16x32_bf16(
                        aY[mi][kk], bX[ni][kk], acc[mi + 4][ni], 0, 0, 0);
                    acc[mi + 4][ni + 2] = __builtin_amdgcn_mfma_f32_16x16x32_bf16(
                        aY[mi][kk], bY[ni][kk], acc[mi + 4][ni + 2], 0, 0, 0);
                }
        __builtin_amdgcn_s_setprio(0);
    }
#undef SBR

    #pragma unroll
    for (int mi = 0; mi < 8; ++mi)
        #pragma unroll
        for (int ni = 0; ni < 4; ++ni) {
            int row = m0 + wm + mi * 16 + lhi * 4;
            int col = n0 + wn + ni * 16 + llo;
            float bcol = bias[col];
            #pragma unroll
            for (int r = 0; r < 4; ++r) {
                size_t idx = (size_t)(row + r) * N + col;
                float v = acc[mi][ni][r] + bcol;
                if (MODE == 2) ((bf16*)C)[idx] = f2bf(gelu_f(v));
                else           ((bf16*)C)[idx] = f2bf(v);
            }
        }
}

// ---------------------------------------------------------------------------
// GEMM: C[M,N] = A[M,K] @ Bt[N,K]^T + bias(fp32), fused epilogue.
// MODE 0: bf16 v | MODE 1: f32 v+res | MODE 2: bf16 gelu(v) | MODE 3: f32 v+res
// Tile TM x 128, BK=64, 4 waves (2x2), 16x16x32 bf16 MFMA. m97 single-buffer
// structure (32 KiB LDS). Used for the N=1024 GEMMs where 256-tiles under-fill
// the grid. Requires K % 64 == 0.
// ---------------------------------------------------------------------------
template <int MODE, int TM>
__global__ __launch_bounds__(256) void gemm_bt(
    const bf16* __restrict__ A, const bf16* __restrict__ Bt,
    const float* __restrict__ bias, const float* __restrict__ res,
    void* __restrict__ C, int M, int N, int K)
{
    constexpr int MI = TM / 32;                 // frags per wave in M
    __shared__ __align__(16) bf16 As[TM * 64];
    __shared__ __align__(16) bf16 Bs[128 * 64];
    const int m0 = blockIdx.x * TM, n0 = blockIdx.y * 128;
    const int t = threadIdx.x;
    const int wave = t >> 6, lane = t & 63, lhi = lane >> 4, llo = lane & 15;
    const int wm = (wave & 1) * (TM / 2), wn = (wave >> 1) * 64;
    const int lrow = lane >> 3;                  // 0..7
    const int lcolsw = ((lane & 7) ^ lrow) * 8;  // swizzled source col group

    const bf16* Ag = A  + (size_t)(m0 + lrow) * K + lcolsw;
    const bf16* Bg = Bt + (size_t)(n0 + lrow) * K + lcolsw;

    f32x4 acc[MI][4];
    for (int i = 0; i < MI; ++i)
        for (int j = 0; j < 4; ++j) acc[i][j] = (f32x4){0.f, 0.f, 0.f, 0.f};

    auto issue = [&](int k0) {
        for (int p = 0; p < TM / 32; ++p) {
            int rb = wave * (TM / 4) + p * 8;
            ld16(Ag + (size_t)rb * K + k0, &As[rb * 64]);
        }
        for (int p = 0; p < 4; ++p) {
            int rb = wave * 32 + p * 8;
            ld16(Bg + (size_t)rb * K + k0, &Bs[rb * 64]);
        }
    };
    auto compute = [&]() {
        for (int kk = 0; kk < 64; kk += 32) {
            const int gb = kk >> 3;
            short8 af[MI], bfr[4];
            for (int i = 0; i < MI; ++i) {
                int row = wm + i * 16 + llo;
                af[i] = *(const short8*)&As[row * 64 + (((gb + lhi) ^ (llo & 7)) * 8)];
            }
            for (int i = 0; i < 4; ++i) {
                int row = wn + i * 16 + llo;
                bfr[i] = *(const short8*)&Bs[row * 64 + (((gb + lhi) ^ (llo & 7)) * 8)];
            }
            for (int mi = 0; mi < MI; ++mi)
                for (int ni = 0; ni < 4; ++ni)
                    acc[mi][ni] = __builtin_amdgcn_mfma_f32_16x16x32_bf16(
                        af[mi], bfr[ni], acc[mi][ni], 0, 0, 0);
        }
    };

    issue(0);
    __syncthreads();
    for (int k0 = 0; ; ) {
        compute();
        k0 += 64;
        if (k0 >= K) break;
        __syncthreads();
        issue(k0);
        __syncthreads();
    }

    for (int mi = 0; mi < MI; ++mi)
        for (int ni = 0; ni < 4; ++ni) {
            int row = m0 + wm + mi * 16 + lhi * 4;
            int col = n0 + wn + ni * 16 + llo;
            float bcol = bias[col];
            for (int r = 0; r < 4; ++r) {
                size_t idx = (size_t)(row + r) * N + col;
                float v = acc[mi][ni][r] + bcol;
                if (MODE == 0) {
                    ((bf16*)C)[idx] = f2bf(v);
                } else if (MODE == 1) {
                    ((float*)C)[idx] = v + res[idx];
                } else if (MODE == 2) {
                    ((bf16*)C)[idx] = f2bf(gelu_f(v));
                } else {
                    ((float*)C)[idx] = v + res[idx];
                }
            }
        }
}

// ---------------------------------------------------------------------------
// Block-local attention: one block per (b, h, seq-block of 64).
// qkv: [8192][3072] bf16 (q | k | v each 1024 wide, head h at col h*64)
// attw: [2048][64][64] fp32 (output 1)   o: [8192][1024] bf16
// ---------------------------------------------------------------------------
__global__ __launch_bounds__(256) void attn_kernel(
    const bf16* __restrict__ qkv, float* __restrict__ attw, bf16* __restrict__ o)
{
    __shared__ __align__(16) bf16 qs[64][LDK];
    __shared__ __align__(16) bf16 ks[64][LDK];
    __shared__ __align__(16) bf16 vs[64][LDK];
    const int gid = blockIdx.x;                 // b*512 + h*32 + blk
    const int blk = gid & 31, h = (gid >> 5) & 15, b = gid >> 9;
    const int t = threadIdx.x, wave = t >> 6, lane = t & 63;
    const int lhi = lane >> 4, llo = lane & 15;
    const int srow = t >> 3, scol = (t & 7) * 8;

    for (int p = 0; p < 2; ++p) {
        int r = p * 32 + srow;
        const bf16* base = qkv + (size_t)(b * 2048 + blk * 64 + r) * 3072 + h * 64 + scol;
        *(short8*)&qs[r][scol] = *(const short8*)(base);
        *(short8*)&ks[r][scol] = *(const short8*)(base + 1024);
        *(short8*)&vs[r][scol] = *(const short8*)(base + 2048);
    }
    __syncthreads();

    // scores: wave handles q-rows [16*wave, 16*wave+16)
    f32x4 sacc[4];
    for (int j = 0; j < 4; ++j) sacc[j] = (f32x4){0.f, 0.f, 0.f, 0.f};
    for (int kk = 0; kk < 64; kk += 32) {
        short8 aq = *(const short8*)&qs[wave * 16 + llo][kk + lhi * 8];
        for (int j = 0; j < 4; ++j) {
            short8 bk = *(const short8*)&ks[j * 16 + llo][kk + lhi * 8];
            sacc[j] = __builtin_amdgcn_mfma_f32_16x16x32_bf16(aq, bk, sacc[j], 0, 0, 0);
        }
    }
    // softmax over 64 cols; row = 16*wave + 4*lhi + r lives in 16 lanes (llo) x 4 j
    float inv[4];
    for (int r = 0; r < 4; ++r) {
        float m = -1e30f;
        for (int j = 0; j < 4; ++j) m = fmaxf(m, sacc[j][r]);
        for (int d = 1; d < 16; d <<= 1) m = fmaxf(m, __shfl_xor(m, d));
        float s = 0.f;
        for (int j = 0; j < 4; ++j) {
            float e = expf((sacc[j][r] - m) * 0.125f);
            sacc[j][r] = e; s += e;
        }
        for (int d = 1; d < 16; d <<= 1) s += __shfl_xor(s, d);
        inv[r] = 1.0f / s;
    }
    __syncthreads();   // everyone done reading qs before we overwrite it with P
    const size_t wbase = (size_t)gid * 4096;
    for (int j = 0; j < 4; ++j)
        for (int r = 0; r < 4; ++r) {
            int row = wave * 16 + lhi * 4 + r, col = j * 16 + llo;
            float pw = sacc[j][r] * inv[r];
            qs[row][col] = f2bf(pw);            // P in A-operand source layout
            attw[wbase + row * 64 + col] = pw;  // output 1 (fp32)
        }
    __syncthreads();

    // O = P @ V
    f32x4 oacc[4];
    for (int nt = 0; nt < 4; ++nt) oacc[nt] = (f32x4){0.f, 0.f, 0.f, 0.f};
    for (int kk = 0; kk < 64; kk += 32) {
        short8 aw = *(const short8*)&qs[wave * 16 + llo][kk + lhi * 8];
        for (int nt = 0; nt < 4; ++nt) {
            short8 bv;
            for (int jj = 0; jj < 8; ++jj)
                bv[jj] = *(const short*)&vs[kk + lhi * 8 + jj][nt * 16 + llo];
            oacc[nt] = __builtin_amdgcn_mfma_f32_16x16x32_bf16(aw, bv, oacc[nt], 0, 0, 0);
        }
    }
    for (int nt = 0; nt < 4; ++nt)
        for (int r = 0; r < 4; ++r) {
            int row = wave * 16 + lhi * 4 + r, col = nt * 16 + llo;
            o[(size_t)(b * 2048 + blk * 64 + row) * 1024 + h * 64 + col] = f2bf(oacc[nt][r]);
        }
}

// ---------------------------------------------------------------------------
extern "C" void kernel_launch(void* const* d_in, const int* in_sizes, int n_in,
                              void* d_out, int out_size, void* d_ws, size_t ws_size,
                              hipStream_t stream)
{
    const float* hidden = (const float*)d_in[0];
    const float* ln1_g  = (const float*)d_in[1];
    const float* ln1_b  = (const float*)d_in[2];
    const float* ln2_g  = (const float*)d_in[3];
    const float* ln2_b  = (const float*)d_in[4];
    const float* wq = (const float*)d_in[5];  const float* bq = (const float*)d_in[6];
    const float* wk = (const float*)d_in[7];  const float* bk = (const float*)d_in[8];
    const float* wv = (const float*)d_in[9];  const float* bv = (const float*)d_in[10];
    const float* wo = (const float*)d_in[11]; const float* bo = (const float*)d_in[12];
    const float* w1 = (const float*)d_in[13]; const float* b1 = (const float*)d_in[14];
    const float* w2 = (const float*)d_in[15]; const float* b2 = (const float*)d_in[16];

    char* ws = (char*)d_ws;
    const size_t MB = 1u << 20;
    bf16*  wqkvT   = (bf16*)(ws +  0 * MB);  // [3072][1024]  6MB
    bf16*  woT     = (bf16*)(ws +  6 * MB);  // [1024][1024]  2MB
    bf16*  w1T     = (bf16*)(ws +  8 * MB);  // [4096][1024]  8MB
    bf16*  w2T     = (bf16*)(ws + 16 * MB);  // [1024][4096]  8MB
    float* biasQKV = (float*)(ws + 24 * MB); // 12KB
    bf16*  x       = (bf16*)(ws + 25 * MB);  // [8192][1024] 16MB (x1 then x2)
    bf16*  qkv     = (bf16*)(ws + 41 * MB);  // [8192][3072] 48MB (dead after attn)
    float* hbuf    = (float*)(ws + 41 * MB); // [8192][1024] fp32 32MB, overlays qkv
    bf16*  ffc     = (bf16*)(ws + 73 * MB);  // [8192][4096] 64MB
    bf16*  obuf    = (bf16*)(ws + 89 * MB);  // [8192][1024] 16MB (dead after gemm<1>)

    float* out0 = (float*)d_out;
    float* attw = (float*)d_out + (size_t)8192 * 1024;

    // 1. weights -> bf16, transposed to [N][K]
    transpose_f32_bf16<<<dim3(16, 16), 256, 0, stream>>>(wq, wqkvT,                 1024, 1024);
    transpose_f32_bf16<<<dim3(16, 16), 256, 0, stream>>>(wk, wqkvT + 1024 * 1024,   1024, 1024);
    transpose_f32_bf16<<<dim3(16, 16), 256, 0, stream>>>(wv, wqkvT + 2*1024*1024,   1024, 1024);
    transpose_f32_bf16<<<dim3(16, 16), 256, 0, stream>>>(wo, woT, 1024, 1024);
    transpose_f32_bf16<<<dim3(64, 16), 256, 0, stream>>>(w1, w1T, 1024, 4096);
    transpose_f32_bf16<<<dim3(16, 64), 256, 0, stream>>>(w2, w2T, 4096, 1024);
    concat_bias<<<12, 256, 0, stream>>>(bq, bk, bv, biasQKV);

    // 2. x1 = LN1(hidden)
    layernorm_k<<<8192, 256, 0, stream>>>(hidden, ln1_g, ln1_b, x);

    // 3. qkv = x1 @ [wq|wk|wv]^T + [bq|bk|bv]   (M=8192, N=3072, K=1024)
    gemm256<0, 1024><<<dim3(32, 12), 512, 0, stream>>>(x, wqkvT, biasQKV, qkv,
                                                       8192, 3072);

    // 4. block attention -> attw (fp32, output 1), obuf (bf16)
    attn_kernel<<<2048, 256, 0, stream>>>(qkv, attw, obuf);

    // 5. h = obuf @ wo^T + bo + hidden   (fp32; qkv region is dead now)
    gemm_bt<1, 128><<<dim3(64, 8), 256, 0, stream>>>(obuf, woT, bo, hidden, hbuf,
                                                     8192, 1024, 1024);

    // 6. x2 = LN2(h)
    layernorm_k<<<8192, 256, 0, stream>>>(hbuf, ln2_g, ln2_b, x);

    // 7. ff1 = gelu(x2 @ w1^T + b1)   (M=8192, N=4096, K=1024)
    gemm256<2, 1024><<<dim3(32, 16), 512, 0, stream>>>(x, w1T, b1, ffc,
                                                       8192, 4096);

    // 8. out0 = ff1 @ w2^T + b2 + h   (M=8192, N=1024, K=4096)
    gemm_bt<3, 128><<<dim3(64, 8), 256, 0, stream>>>(ffc, w2T, b2, hbuf, out0,
                                                     8192, 1024, 4096);
}